// Round 1
// baseline (431.907 us; speedup 1.0000x reference)
//
#include <hip/hip_runtime.h>

static constexpr int C  = 512;
static constexpr int H  = 64;
static constexpr int W  = 64;
static constexpr int P  = 4096;    // H*W
static constexpr int CC = 262144;  // 512*512

__device__ __forceinline__ int refl(int q) { return q < 0 ? 1 : (q > 63 ? 62 : q); }

// ---------------- zero small scratch (sqn_c, sqn_s, ..., msum, acc) ----------------
__global__ void k_init(float* __restrict__ small) {
    int e = blockIdx.x * 256 + threadIdx.x;
    if (e < 16386) small[e] = 0.0f;
}

// ---------------- per-pixel squared channel norms (content & style) ----------------
__global__ void k_sqn(const float* __restrict__ content, const float* __restrict__ style,
                      float* __restrict__ sqn_c, float* __restrict__ sqn_s) {
    int p  = (blockIdx.x & 15) * 256 + threadIdx.x;
    int c0 = (blockIdx.x >> 4) * 64;   // 8 channel slices of 64
    float sc = 0.f, ss = 0.f;
    for (int c = c0; c < c0 + 64; ++c) {
        float a = content[c * P + p]; sc += a * a;
        float b = style[c * P + p];   ss += b * b;
    }
    atomicAdd(&sqn_c[p], sc);
    atomicAdd(&sqn_s[p], ss);
}

// ---------------- 3x3 reflect box-sum + sqrt -> patch norms ----------------
__global__ void k_pnorm(const float* __restrict__ sqn_c, const float* __restrict__ sqn_s,
                        float* __restrict__ c_norm, float* __restrict__ s_norm) {
    int p = blockIdx.x * 256 + threadIdx.x;
    int i = p >> 6, j = p & 63;
    float s1 = 0.f, s2 = 0.f;
    #pragma unroll
    for (int dh = -1; dh <= 1; ++dh) {
        int ih = refl(i + dh);
        #pragma unroll
        for (int dw = -1; dw <= 1; ++dw) {
            int jw = refl(j + dw);
            s1 += sqn_c[ih * 64 + jw];
            s2 += sqn_s[ih * 64 + jw];
        }
    }
    c_norm[p] = sqrtf(s1);
    s_norm[p] = sqrtf(s2);
}

// ---------------- mask sum ----------------
__global__ void k_msum(const float* __restrict__ mask, float* __restrict__ msum) {
    __shared__ float red[256];
    float s = 0.f;
    for (int e = threadIdx.x; e < P; e += 256) s += mask[e];
    red[threadIdx.x] = s;
    __syncthreads();
    for (int t = 128; t > 0; t >>= 1) {
        if (threadIdx.x < t) red[threadIdx.x] += red[threadIdx.x + t];
        __syncthreads();
    }
    if (threadIdx.x == 0) msum[0] = red[0];
}

// ---------------- D0 = content^T * style  (4096x4096, K=512), fp32 tiled ----------------
// 128x128 tile per block, 256 threads, 8x8 per thread, BK=8
__global__ __launch_bounds__(256) void k_gemm(const float* __restrict__ A,
                                              const float* __restrict__ B,
                                              float* __restrict__ D0) {
    __shared__ float As[8][128];
    __shared__ float Bs[8][128];
    const int tid = threadIdx.x;
    const int tx = tid & 15, ty = tid >> 4;
    const int i0 = blockIdx.y * 128, j0 = blockIdx.x * 128;
    const int lk = tid >> 5;            // 0..7
    const int lc = (tid & 31) << 2;     // 0..124

    float acc[8][8] = {};

    for (int kk = 0; kk < C; kk += 8) {
        float4 av = *(const float4*)(A + (kk + lk) * P + i0 + lc);
        float4 bv = *(const float4*)(B + (kk + lk) * P + j0 + lc);
        __syncthreads();   // previous iteration's compute done before overwrite
        *(float4*)&As[lk][lc] = av;
        *(float4*)&Bs[lk][lc] = bv;
        __syncthreads();
        #pragma unroll
        for (int k = 0; k < 8; ++k) {
            float a[8], b[8];
            *(float4*)&a[0] = *(const float4*)&As[k][ty * 8];
            *(float4*)&a[4] = *(const float4*)&As[k][ty * 8 + 4];
            *(float4*)&b[0] = *(const float4*)&Bs[k][tx * 4];
            *(float4*)&b[4] = *(const float4*)&Bs[k][64 + tx * 4];
            #pragma unroll
            for (int u = 0; u < 8; ++u)
                #pragma unroll
                for (int v = 0; v < 8; ++v)
                    acc[u][v] = fmaf(a[u], b[v], acc[u][v]);
        }
    }

    #pragma unroll
    for (int u = 0; u < 8; ++u) {
        int irow = i0 + ty * 8 + u;
        float4 o1 = make_float4(acc[u][0], acc[u][1], acc[u][2], acc[u][3]);
        float4 o2 = make_float4(acc[u][4], acc[u][5], acc[u][6], acc[u][7]);
        *(float4*)(D0 + (size_t)irow * P + j0 + tx * 4)      = o1;
        *(float4*)(D0 + (size_t)irow * P + j0 + 64 + tx * 4) = o2;
    }
}

// ---------------- 9-shift score + normalize + argmax per content location ----------------
__global__ __launch_bounds__(256) void k_argmax(const float* __restrict__ D0,
                                                const float* __restrict__ c_norm,
                                                const float* __restrict__ s_norm,
                                                int* __restrict__ idxOut) {
    const int i = blockIdx.x;
    const int ih = i >> 6, iw = i & 63;
    const float cn = c_norm[i];
    int rb[9];
    #pragma unroll
    for (int t = 0; t < 9; ++t) {
        int dh = t / 3 - 1, dw = t % 3 - 1;
        rb[t] = (refl(ih + dh) * 64 + refl(iw + dw)) * P;
    }
    float best = -1e30f;
    int bidx = 0;
    for (int j = threadIdx.x; j < P; j += 256) {
        int jh = j >> 6, jw = j & 63;
        int hm = (jh == 0) ? 1 : jh - 1;
        int hp = (jh == 63) ? 62 : jh + 1;
        int wm = (jw == 0) ? 1 : jw - 1;
        int wp = (jw == 63) ? 62 : jw + 1;
        float s = D0[rb[0] + hm * 64 + wm] + D0[rb[1] + hm * 64 + jw] + D0[rb[2] + hm * 64 + wp]
                + D0[rb[3] + jh * 64 + wm] + D0[rb[4] + jh * 64 + jw] + D0[rb[5] + jh * 64 + wp]
                + D0[rb[6] + hp * 64 + wm] + D0[rb[7] + hp * 64 + jw] + D0[rb[8] + hp * 64 + wp];
        float v = s / (cn * s_norm[j] + 1e-9f);
        if (v > best) { best = v; bidx = j; }   // per-thread j increasing -> first occurrence kept
    }
    __shared__ float bv[256];
    __shared__ int   bi[256];
    bv[threadIdx.x] = best;
    bi[threadIdx.x] = bidx;
    __syncthreads();
    for (int t = 128; t > 0; t >>= 1) {
        if (threadIdx.x < t) {
            float ov = bv[threadIdx.x + t];
            int   oi = bi[threadIdx.x + t];
            if (ov > bv[threadIdx.x] || (ov == bv[threadIdx.x] && oi < bi[threadIdx.x])) {
                bv[threadIdx.x] = ov;
                bi[threadIdx.x] = oi;
            }
        }
        __syncthreads();
    }
    if (threadIdx.x == 0) idxOut[i] = bi[0];
}

// ---------------- build masked matrices: fc = gather(style, idx)*mask, fg = input*mask ----------------
__global__ void k_build(const float* __restrict__ style, const float* __restrict__ input,
                        const float* __restrict__ mask, const int* __restrict__ idx,
                        float* __restrict__ fc, float* __restrict__ fg) {
    int e = blockIdx.x * 256 + threadIdx.x;
    int p = e & (P - 1);
    int c = e >> 12;
    float m = mask[p];
    fc[e] = style[(c << 12) + idx[p]] * m;
    fg[e] = input[e] * m;
}

// ---------------- gram difference partials: part[z] += (fg fg^T - fc fc^T) over p-chunk z ----------------
// out tile 64x64, 256 threads, 4x4 per thread, BK=32, K-chunk 512 per z
__global__ __launch_bounds__(256) void k_gram(const float* __restrict__ fc,
                                              const float* __restrict__ fg,
                                              float* __restrict__ part) {
    __shared__ float Ag[32][68];
    __shared__ float Bg[32][68];
    __shared__ float Ac[32][68];
    __shared__ float Bc[32][68];
    const int tid = threadIdx.x;
    const int tx = tid & 15, ty = tid >> 4;
    const int a0 = blockIdx.y * 64, b0 = blockIdx.x * 64;
    const int z = blockIdx.z;

    float accg[4][4] = {};
    float accc[4][4] = {};

    for (int p0 = z * 512; p0 < z * 512 + 512; p0 += 32) {
        float4 vg[2], wg[2], vc[2], wc[2];
        int rows[2], cols[2];
        #pragma unroll
        for (int r = 0; r < 2; ++r) {
            int q = tid + r * 256;
            rows[r] = q >> 3;
            cols[r] = (q & 7) * 4;
            vg[r] = *(const float4*)(fg + (a0 + rows[r]) * P + p0 + cols[r]);
            wg[r] = *(const float4*)(fg + (b0 + rows[r]) * P + p0 + cols[r]);
            vc[r] = *(const float4*)(fc + (a0 + rows[r]) * P + p0 + cols[r]);
            wc[r] = *(const float4*)(fc + (b0 + rows[r]) * P + p0 + cols[r]);
        }
        __syncthreads();   // previous compute done
        #pragma unroll
        for (int r = 0; r < 2; ++r) {
            int row = rows[r], c4 = cols[r];
            Ag[c4 + 0][row] = vg[r].x; Ag[c4 + 1][row] = vg[r].y; Ag[c4 + 2][row] = vg[r].z; Ag[c4 + 3][row] = vg[r].w;
            Bg[c4 + 0][row] = wg[r].x; Bg[c4 + 1][row] = wg[r].y; Bg[c4 + 2][row] = wg[r].z; Bg[c4 + 3][row] = wg[r].w;
            Ac[c4 + 0][row] = vc[r].x; Ac[c4 + 1][row] = vc[r].y; Ac[c4 + 2][row] = vc[r].z; Ac[c4 + 3][row] = vc[r].w;
            Bc[c4 + 0][row] = wc[r].x; Bc[c4 + 1][row] = wc[r].y; Bc[c4 + 2][row] = wc[r].z; Bc[c4 + 3][row] = wc[r].w;
        }
        __syncthreads();
        #pragma unroll
        for (int p = 0; p < 32; ++p) {
            float4 a1 = *(const float4*)&Ag[p][ty * 4];
            float4 b1 = *(const float4*)&Bg[p][tx * 4];
            float4 a2 = *(const float4*)&Ac[p][ty * 4];
            float4 b2 = *(const float4*)&Bc[p][tx * 4];
            float a1r[4] = {a1.x, a1.y, a1.z, a1.w};
            float b1r[4] = {b1.x, b1.y, b1.z, b1.w};
            float a2r[4] = {a2.x, a2.y, a2.z, a2.w};
            float b2r[4] = {b2.x, b2.y, b2.z, b2.w};
            #pragma unroll
            for (int u = 0; u < 4; ++u)
                #pragma unroll
                for (int v = 0; v < 4; ++v) {
                    accg[u][v] = fmaf(a1r[u], b1r[v], accg[u][v]);
                    accc[u][v] = fmaf(a2r[u], b2r[v], accc[u][v]);
                }
        }
        __syncthreads();
    }

    #pragma unroll
    for (int u = 0; u < 4; ++u) {
        float4 o = make_float4(accg[u][0] - accc[u][0], accg[u][1] - accc[u][1],
                               accg[u][2] - accc[u][2], accg[u][3] - accc[u][3]);
        *(float4*)(part + (size_t)z * CC + (a0 + ty * 4 + u) * 512 + b0 + tx * 4) = o;
    }
}

// ---------------- sum of squared diffs ----------------
__global__ void k_loss(const float* __restrict__ part, float* __restrict__ acc) {
    int e = blockIdx.x * 256 + threadIdx.x;
    float d = 0.f;
    #pragma unroll
    for (int z = 0; z < 8; ++z) d += part[z * CC + e];
    __shared__ float red[256];
    red[threadIdx.x] = d * d;
    __syncthreads();
    for (int t = 128; t > 0; t >>= 1) {
        if (threadIdx.x < t) red[threadIdx.x] += red[threadIdx.x + t];
        __syncthreads();
    }
    if (threadIdx.x == 0) atomicAdd(acc, red[0]);
}

__global__ void k_final(const float* __restrict__ msum, const float* __restrict__ acc,
                        float* __restrict__ out) {
    float m = msum[0];
    out[0] = acc[0] * 100.0f / (m * m * 262144.0f);
}

extern "C" void kernel_launch(void* const* d_in, const int* in_sizes, int n_in,
                              void* d_out, int out_size, void* d_ws, size_t ws_size,
                              hipStream_t stream) {
    (void)in_sizes; (void)n_in; (void)out_size; (void)ws_size;
    const float* content = (const float*)d_in[0];
    const float* style   = (const float*)d_in[1];
    const float* input   = (const float*)d_in[2];
    const float* mask    = (const float*)d_in[3];

    float* ws    = (float*)d_ws;
    float* D0    = ws;                  // 4096*4096 floats (64 MB)
    float* fc    = ws;                  // reuses D0 region after argmax
    float* fg    = ws + 2097152;
    float* part  = ws + 4194304;        // 8 * 262144 floats
    float* small = ws + 16777216;
    float* sqn_c  = small;
    float* sqn_s  = small + 4096;
    float* c_norm = small + 8192;
    float* s_norm = small + 12288;
    float* msum   = small + 16384;
    float* acc    = small + 16385;
    int*   idx    = (int*)(small + 16386);
    float* out = (float*)d_out;

    k_init  <<<65, 256, 0, stream>>>(small);
    k_sqn   <<<128, 256, 0, stream>>>(content, style, sqn_c, sqn_s);
    k_pnorm <<<16, 256, 0, stream>>>(sqn_c, sqn_s, c_norm, s_norm);
    k_msum  <<<1, 256, 0, stream>>>(mask, msum);
    k_gemm  <<<dim3(32, 32), 256, 0, stream>>>(content, style, D0);
    k_argmax<<<4096, 256, 0, stream>>>(D0, c_norm, s_norm, idx);
    k_build <<<8192, 256, 0, stream>>>(style, input, mask, idx, fc, fg);
    k_gram  <<<dim3(8, 8, 8), 256, 0, stream>>>(fc, fg, part);
    k_loss  <<<1024, 256, 0, stream>>>(part, acc);
    k_final <<<1, 1, 0, stream>>>(msum, acc, out);
}

// Round 2
// 186.948 us; speedup vs baseline: 2.3103x; 2.3103x over previous
//
#include <hip/hip_runtime.h>

static constexpr int C  = 512;
static constexpr int P  = 4096;    // H*W
static constexpr int CC = 262144;  // 512*512

typedef _Float16 half8 __attribute__((ext_vector_type(8)));
typedef float    f32x4 __attribute__((ext_vector_type(4)));

__device__ __forceinline__ int refl(int q) { return q < 0 ? 1 : (q > 63 ? 62 : q); }

__device__ __forceinline__ void g2l16(const void* g, const void* l) {
    __builtin_amdgcn_global_load_lds((const __attribute__((address_space(1))) unsigned int*)g,
                                     (__attribute__((address_space(3))) unsigned int*)l, 16, 0, 0);
}

// ---------------- zero small scratch ----------------
__global__ void k_init(float* __restrict__ small) {
    int e = blockIdx.x * 256 + threadIdx.x;
    if (e < 16386) small[e] = 0.0f;
}

// ---------------- transpose fp32 [c][p] -> fp16 [p][c], fused squared-norm ----------------
__global__ __launch_bounds__(256) void k_prep(const float* __restrict__ content, const float* __restrict__ style,
                                              _Float16* __restrict__ Ah, _Float16* __restrict__ Bh,
                                              float* __restrict__ sqn_c, float* __restrict__ sqn_s) {
    __shared__ float T[64][65];
    const int p0 = (blockIdx.x & 63) * 64, c0 = (blockIdx.x >> 6) * 64;
    const int pl = threadIdx.x & 63, cq = threadIdx.x >> 6;   // read role
    const int cl2 = threadIdx.x & 63, pq = threadIdx.x >> 6;  // write role

    // content
    float sq = 0.f;
    #pragma unroll
    for (int r = 0; r < 16; ++r) {
        int cl = cq + r * 4;
        float v = content[(size_t)(c0 + cl) * P + p0 + pl];
        T[cl][pl] = v;
        sq += v * v;
    }
    atomicAdd(&sqn_c[p0 + pl], sq);
    __syncthreads();
    #pragma unroll
    for (int r = 0; r < 16; ++r) {
        int pl2 = pq + r * 4;
        Ah[(size_t)(p0 + pl2) * C + c0 + cl2] = (_Float16)T[cl2][pl2];
    }
    __syncthreads();

    // style
    sq = 0.f;
    #pragma unroll
    for (int r = 0; r < 16; ++r) {
        int cl = cq + r * 4;
        float v = style[(size_t)(c0 + cl) * P + p0 + pl];
        T[cl][pl] = v;
        sq += v * v;
    }
    atomicAdd(&sqn_s[p0 + pl], sq);
    __syncthreads();
    #pragma unroll
    for (int r = 0; r < 16; ++r) {
        int pl2 = pq + r * 4;
        Bh[(size_t)(p0 + pl2) * C + c0 + cl2] = (_Float16)T[cl2][pl2];
    }
}

// ---------------- 3x3 reflect box-sum + sqrt -> patch norms ----------------
__global__ void k_pnorm(const float* __restrict__ sqn_c, const float* __restrict__ sqn_s,
                        float* __restrict__ c_norm, float* __restrict__ s_norm) {
    int p = blockIdx.x * 256 + threadIdx.x;
    int i = p >> 6, j = p & 63;
    float s1 = 0.f, s2 = 0.f;
    #pragma unroll
    for (int dh = -1; dh <= 1; ++dh) {
        int ih = refl(i + dh);
        #pragma unroll
        for (int dw = -1; dw <= 1; ++dw) {
            int jw = refl(j + dw);
            s1 += sqn_c[ih * 64 + jw];
            s2 += sqn_s[ih * 64 + jw];
        }
    }
    c_norm[p] = sqrtf(s1);
    s_norm[p] = sqrtf(s2);
}

// ---------------- mask sum ----------------
__global__ void k_msum(const float* __restrict__ mask, float* __restrict__ msum) {
    __shared__ float red[256];
    float s = 0.f;
    for (int e = threadIdx.x; e < P; e += 256) s += mask[e];
    red[threadIdx.x] = s;
    __syncthreads();
    for (int t = 128; t > 0; t >>= 1) {
        if (threadIdx.x < t) red[threadIdx.x] += red[threadIdx.x + t];
        __syncthreads();
    }
    if (threadIdx.x == 0) msum[0] = red[0];
}

// ---------------- D0 = Ah * Bh^T (4096x4096, K=512), fp16 MFMA, fp32 accum, fp16 out ----------------
// 128x128 tile, BK=32, 4 waves (2x2), 16x16x32 MFMA, swizzled global_load_lds staging
__global__ __launch_bounds__(256) void k_gemm16(const _Float16* __restrict__ Ah,
                                                const _Float16* __restrict__ Bh,
                                                _Float16* __restrict__ D0h) {
    __shared__ _Float16 As[128 * 32];
    __shared__ _Float16 Bs[128 * 32];
    const int tid = threadIdx.x;
    const int wave = tid >> 6, lane = tid & 63;
    const int wr = wave >> 1, wc = wave & 1;
    const int quad = lane >> 4, l15 = lane & 15;
    const int i0 = blockIdx.y * 128, j0 = blockIdx.x * 128;

    // staging: wave handles local rows [wave*32, wave*32+32) of both tiles, two 16-row calls each
    const int m1 = wave * 32 + (lane >> 2);
    const int m2 = m1 + 16;
    const int gl1 = (lane & 3) ^ ((m1 >> 1) & 3);  // logical k-granule fetched into phys granule lane%4
    const int gl2 = (lane & 3) ^ ((m2 >> 1) & 3);
    const _Float16* gA1 = Ah + (size_t)(i0 + m1) * C + gl1 * 8;
    const _Float16* gA2 = Ah + (size_t)(i0 + m2) * C + gl2 * 8;
    const _Float16* gB1 = Bh + (size_t)(j0 + m1) * C + gl1 * 8;
    const _Float16* gB2 = Bh + (size_t)(j0 + m2) * C + gl2 * 8;
    _Float16* lA1 = As + wave * 1024;
    _Float16* lA2 = As + wave * 1024 + 512;
    _Float16* lB1 = Bs + wave * 1024;
    _Float16* lB2 = Bs + wave * 1024 + 512;

    // fragment LDS offsets (halfs), swizzle-adjusted
    int aoff[4], boff[4];
    #pragma unroll
    for (int mi = 0; mi < 4; ++mi) {
        int m = wr * 64 + mi * 16 + l15;
        aoff[mi] = m * 32 + (quad ^ ((m >> 1) & 3)) * 8;
        int n = wc * 64 + mi * 16 + l15;
        boff[mi] = n * 32 + (quad ^ ((n >> 1) & 3)) * 8;
    }

    f32x4 acc[4][4] = {};

    for (int kk = 0; kk < C; kk += 32) {
        __syncthreads();
        g2l16(gA1, lA1); g2l16(gA2, lA2);
        g2l16(gB1, lB1); g2l16(gB2, lB2);
        gA1 += 32; gA2 += 32; gB1 += 32; gB2 += 32;
        __syncthreads();
        half8 af[4], bf[4];
        #pragma unroll
        for (int mi = 0; mi < 4; ++mi) af[mi] = *(const half8*)(As + aoff[mi]);
        #pragma unroll
        for (int ni = 0; ni < 4; ++ni) bf[ni] = *(const half8*)(Bs + boff[ni]);
        #pragma unroll
        for (int mi = 0; mi < 4; ++mi)
            #pragma unroll
            for (int ni = 0; ni < 4; ++ni)
                acc[mi][ni] = __builtin_amdgcn_mfma_f32_16x16x32_f16(af[mi], bf[ni], acc[mi][ni], 0, 0, 0);
    }

    #pragma unroll
    for (int mi = 0; mi < 4; ++mi) {
        int row = i0 + wr * 64 + mi * 16 + quad * 4;
        #pragma unroll
        for (int ni = 0; ni < 4; ++ni) {
            int col = j0 + wc * 64 + ni * 16 + l15;
            #pragma unroll
            for (int r = 0; r < 4; ++r)
                D0h[(size_t)(row + r) * P + col] = (_Float16)acc[mi][ni][r];
        }
    }
}

// ---------------- 9-shift score + normalize + argmax ----------------
__global__ __launch_bounds__(256) void k_argmax(const _Float16* __restrict__ D0h,
                                                const float* __restrict__ c_norm,
                                                const float* __restrict__ s_norm,
                                                int* __restrict__ idxOut) {
    const int i = blockIdx.x;
    const int ih = i >> 6, iw = i & 63;
    const float cn = c_norm[i];
    int rb[9];
    #pragma unroll
    for (int t = 0; t < 9; ++t) {
        int dh = t / 3 - 1, dw = t % 3 - 1;
        rb[t] = (refl(ih + dh) * 64 + refl(iw + dw)) * P;
    }
    float best = -1e30f;
    int bidx = 0;
    for (int j = threadIdx.x; j < P; j += 256) {
        int jh = j >> 6, jw = j & 63;
        int hm = (jh == 0) ? 1 : jh - 1;
        int hp = (jh == 63) ? 62 : jh + 1;
        int wm = (jw == 0) ? 1 : jw - 1;
        int wp = (jw == 63) ? 62 : jw + 1;
        float s = (float)D0h[rb[0] + hm * 64 + wm] + (float)D0h[rb[1] + hm * 64 + jw] + (float)D0h[rb[2] + hm * 64 + wp]
                + (float)D0h[rb[3] + jh * 64 + wm] + (float)D0h[rb[4] + jh * 64 + jw] + (float)D0h[rb[5] + jh * 64 + wp]
                + (float)D0h[rb[6] + hp * 64 + wm] + (float)D0h[rb[7] + hp * 64 + jw] + (float)D0h[rb[8] + hp * 64 + wp];
        float v = s / (cn * s_norm[j] + 1e-9f);
        if (v > best) { best = v; bidx = j; }
    }
    __shared__ float bv[256];
    __shared__ int   bi[256];
    bv[threadIdx.x] = best;
    bi[threadIdx.x] = bidx;
    __syncthreads();
    for (int t = 128; t > 0; t >>= 1) {
        if (threadIdx.x < t) {
            float ov = bv[threadIdx.x + t];
            int   oi = bi[threadIdx.x + t];
            if (ov > bv[threadIdx.x] || (ov == bv[threadIdx.x] && oi < bi[threadIdx.x])) {
                bv[threadIdx.x] = ov;
                bi[threadIdx.x] = oi;
            }
        }
        __syncthreads();
    }
    if (threadIdx.x == 0) idxOut[i] = bi[0];
}

// ---------------- build masked fp16 matrices ----------------
__global__ void k_build(const float* __restrict__ style, const float* __restrict__ input,
                        const float* __restrict__ mask, const int* __restrict__ idx,
                        _Float16* __restrict__ fc, _Float16* __restrict__ fg) {
    int t = blockIdx.x * 256 + threadIdx.x;    // 262144 threads, 8 elems each
    int e0 = t * 8;
    int p0 = e0 & (P - 1), c = e0 >> 12;
    half8 vg, vc;
    #pragma unroll
    for (int u = 0; u < 8; ++u) {
        float m = mask[p0 + u];
        vg[u] = (_Float16)(input[e0 + u] * m);
        vc[u] = (_Float16)(style[(c << 12) + idx[p0 + u]] * m);
    }
    *(half8*)(fg + e0) = vg;
    *(half8*)(fc + e0) = vc;
}

// ---------------- gram partials via MFMA, fragments direct from global ----------------
// grid (4,4,32): z<16 -> fg partial (K-chunk z*256), z>=16 -> fc partial (K-chunk (z-16)*256)
__global__ __launch_bounds__(256) void k_gram(const _Float16* __restrict__ fg,
                                              const _Float16* __restrict__ fc,
                                              float* __restrict__ part) {
    const int z = blockIdx.z;
    const _Float16* M = (z < 16) ? fg : fc;
    const int p0 = (z & 15) * 256;
    const int wave = threadIdx.x >> 6, lane = threadIdx.x & 63;
    const int wr = wave >> 1, wc = wave & 1, quad = lane >> 4, l15 = lane & 15;
    const int a0 = blockIdx.y * 128 + wr * 64, b0 = blockIdx.x * 128 + wc * 64;

    f32x4 acc[4][4] = {};
    for (int ks = 0; ks < 256; ks += 32) {
        int kbase = p0 + ks + quad * 8;
        half8 af[4], bf[4];
        #pragma unroll
        for (int mi = 0; mi < 4; ++mi) af[mi] = *(const half8*)(M + (size_t)(a0 + mi * 16 + l15) * P + kbase);
        #pragma unroll
        for (int ni = 0; ni < 4; ++ni) bf[ni] = *(const half8*)(M + (size_t)(b0 + ni * 16 + l15) * P + kbase);
        #pragma unroll
        for (int mi = 0; mi < 4; ++mi)
            #pragma unroll
            for (int ni = 0; ni < 4; ++ni)
                acc[mi][ni] = __builtin_amdgcn_mfma_f32_16x16x32_f16(af[mi], bf[ni], acc[mi][ni], 0, 0, 0);
    }
    #pragma unroll
    for (int mi = 0; mi < 4; ++mi)
        #pragma unroll
        for (int ni = 0; ni < 4; ++ni)
            #pragma unroll
            for (int r = 0; r < 4; ++r)
                part[(size_t)z * CC + (size_t)(a0 + mi * 16 + quad * 4 + r) * C + b0 + ni * 16 + l15] = acc[mi][ni][r];
}

// ---------------- loss: (sum_fg - sum_fc)^2 reduced ----------------
__global__ void k_loss(const float* __restrict__ part, float* __restrict__ acc) {
    int e = blockIdx.x * 256 + threadIdx.x;
    float d = 0.f;
    #pragma unroll
    for (int z = 0; z < 16; ++z) d += part[(size_t)z * CC + e];
    #pragma unroll
    for (int z = 16; z < 32; ++z) d -= part[(size_t)z * CC + e];
    __shared__ float red[256];
    red[threadIdx.x] = d * d;
    __syncthreads();
    for (int t = 128; t > 0; t >>= 1) {
        if (threadIdx.x < t) red[threadIdx.x] += red[threadIdx.x + t];
        __syncthreads();
    }
    if (threadIdx.x == 0) atomicAdd(acc, red[0]);
}

__global__ void k_final(const float* __restrict__ msum, const float* __restrict__ acc,
                        float* __restrict__ out) {
    float m = msum[0];
    out[0] = acc[0] * 100.0f / (m * m * 262144.0f);
}

extern "C" void kernel_launch(void* const* d_in, const int* in_sizes, int n_in,
                              void* d_out, int out_size, void* d_ws, size_t ws_size,
                              hipStream_t stream) {
    (void)in_sizes; (void)n_in; (void)out_size; (void)ws_size;
    const float* content = (const float*)d_in[0];
    const float* style   = (const float*)d_in[1];
    const float* input   = (const float*)d_in[2];
    const float* mask    = (const float*)d_in[3];

    char* ws = (char*)d_ws;
    _Float16* D0h  = (_Float16*)ws;                        // 32 MB (dead after k_argmax)
    float*    part = (float*)ws;                           // 32 MB (overlays D0h)
    _Float16* Ah   = (_Float16*)(ws + (32u << 20));        // 4 MB
    _Float16* Bh   = (_Float16*)(ws + (36u << 20));        // 4 MB
    _Float16* fg_h = (_Float16*)(ws + (40u << 20));        // 4 MB
    _Float16* fc_h = (_Float16*)(ws + (44u << 20));        // 4 MB
    float*    small = (float*)(ws + (48u << 20));
    float* sqn_c  = small;
    float* sqn_s  = small + 4096;
    float* c_norm = small + 8192;
    float* s_norm = small + 12288;
    float* msum   = small + 16384;
    float* acc    = small + 16385;
    int*   idx    = (int*)(small + 16386);
    float* out = (float*)d_out;

    k_init  <<<65, 256, 0, stream>>>(small);
    k_prep  <<<512, 256, 0, stream>>>(content, style, Ah, Bh, sqn_c, sqn_s);
    k_pnorm <<<16, 256, 0, stream>>>(sqn_c, sqn_s, c_norm, s_norm);
    k_msum  <<<1, 256, 0, stream>>>(mask, msum);
    k_gemm16<<<dim3(32, 32), 256, 0, stream>>>(Ah, Bh, D0h);
    k_argmax<<<4096, 256, 0, stream>>>(D0h, c_norm, s_norm, idx);
    k_build <<<1024, 256, 0, stream>>>(style, input, mask, idx, fc_h, fg_h);
    k_gram  <<<dim3(4, 4, 32), 256, 0, stream>>>(fg_h, fc_h, part);
    k_loss  <<<1024, 256, 0, stream>>>(part, acc);
    k_final <<<1, 1, 0, stream>>>(msum, acc, out);
}

// Round 3
// 173.801 us; speedup vs baseline: 2.4851x; 1.0756x over previous
//
#include <hip/hip_runtime.h>

static constexpr int C  = 512;
static constexpr int P  = 4096;    // H*W
static constexpr int CC = 262144;  // 512*512

typedef _Float16 half8  __attribute__((ext_vector_type(8)));
typedef _Float16 half2v __attribute__((ext_vector_type(2)));
typedef float    f32x4  __attribute__((ext_vector_type(4)));

__device__ __forceinline__ int refl(int q) { return q < 0 ? 1 : (q > 63 ? 62 : q); }

__device__ __forceinline__ void g2l16(const void* g, const void* l) {
    __builtin_amdgcn_global_load_lds((const __attribute__((address_space(1))) unsigned int*)g,
                                     (__attribute__((address_space(3))) unsigned int*)l, 16, 0, 0);
}

// ---------------- zero small scratch: sqn_s (4096) + acc (1) ----------------
__global__ void k_init(float* __restrict__ small) {
    int e = blockIdx.x * 256 + threadIdx.x;
    if (e < 4096) small[e] = 0.0f;          // sqn_s
    if (e == 4096) small[8193] = 0.0f;      // acc
}

// ---------------- transpose fp32 [c][p] -> fp16 [p][c]; style squared-norm ----------------
__global__ __launch_bounds__(256) void k_prep(const float* __restrict__ content, const float* __restrict__ style,
                                              _Float16* __restrict__ Ah, _Float16* __restrict__ Bh,
                                              float* __restrict__ sqn_s) {
    __shared__ float T[64][65];
    const int p0 = (blockIdx.x & 63) * 64, c0 = (blockIdx.x >> 6) * 64;
    const int pl = threadIdx.x & 63, cq = threadIdx.x >> 6;   // read role
    const int cl2 = threadIdx.x & 63, pq = threadIdx.x >> 6;  // write role

    // content (no norm needed: c_norm constant over j -> dropped from argmax)
    #pragma unroll
    for (int r = 0; r < 16; ++r) {
        int cl = cq + r * 4;
        T[cl][pl] = content[(size_t)(c0 + cl) * P + p0 + pl];
    }
    __syncthreads();
    #pragma unroll
    for (int r = 0; r < 16; ++r) {
        int pl2 = pq + r * 4;
        Ah[(size_t)(p0 + pl2) * C + c0 + cl2] = (_Float16)T[cl2][pl2];
    }
    __syncthreads();

    // style
    float sq = 0.f;
    #pragma unroll
    for (int r = 0; r < 16; ++r) {
        int cl = cq + r * 4;
        float v = style[(size_t)(c0 + cl) * P + p0 + pl];
        T[cl][pl] = v;
        sq += v * v;
    }
    atomicAdd(&sqn_s[p0 + pl], sq);
    __syncthreads();
    #pragma unroll
    for (int r = 0; r < 16; ++r) {
        int pl2 = pq + r * 4;
        Bh[(size_t)(p0 + pl2) * C + c0 + cl2] = (_Float16)T[cl2][pl2];
    }
}

// ---------------- 3x3 reflect box-sum -> 1/patch_norm; block 0 also reduces mask sum ----------------
__global__ void k_pnorm(const float* __restrict__ sqn_s, const float* __restrict__ mask,
                        float* __restrict__ inv_sn, float* __restrict__ msum) {
    int p = blockIdx.x * 256 + threadIdx.x;
    int i = p >> 6, j = p & 63;
    float s2 = 0.f;
    #pragma unroll
    for (int dh = -1; dh <= 1; ++dh) {
        int ih = refl(i + dh);
        #pragma unroll
        for (int dw = -1; dw <= 1; ++dw)
            s2 += sqn_s[ih * 64 + refl(j + dw)];
    }
    inv_sn[p] = 1.0f / sqrtf(s2);

    if (blockIdx.x == 0) {
        __shared__ float red[256];
        float s = 0.f;
        for (int e = threadIdx.x; e < P; e += 256) s += mask[e];
        red[threadIdx.x] = s;
        __syncthreads();
        for (int t = 128; t > 0; t >>= 1) {
            if (threadIdx.x < t) red[threadIdx.x] += red[threadIdx.x + t];
            __syncthreads();
        }
        if (threadIdx.x == 0) msum[0] = red[0];
    }
}

// ---------------- D0 = Ah * Bh^T (4096x4096, K=512), fp16 MFMA, BK=64 m97-style ----------------
__global__ __launch_bounds__(256) void k_gemm16(const _Float16* __restrict__ Ah,
                                                const _Float16* __restrict__ Bh,
                                                _Float16* __restrict__ D0h) {
    __shared__ _Float16 As[128 * 64];
    __shared__ _Float16 Bs[128 * 64];
    const int tid = threadIdx.x;
    const int wave = tid >> 6, lane = tid & 63;
    const int wr = wave >> 1, wc = wave & 1;
    const int quad = lane >> 4, l15 = lane & 15;
    const int i0 = blockIdx.y * 128, j0 = blockIdx.x * 128;

    // staging: wave covers rows [wave*32, wave*32+32), 4 calls of 8 rows each; 8 granules/row
    int mloc[4], goff[4];
    #pragma unroll
    for (int c2 = 0; c2 < 4; ++c2) {
        int m = wave * 32 + c2 * 8 + (lane >> 3);
        mloc[c2] = m;
        goff[c2] = ((lane & 7) ^ (m & 7)) * 8;   // logical granule fetched into phys slot lane&7
    }

    // fragment LDS offsets (halfs), swizzle-adjusted: phys = (quad + 4*kh) ^ (m&7)
    int aoff[4][2], boff[4][2];
    #pragma unroll
    for (int mi = 0; mi < 4; ++mi) {
        int m = wr * 64 + mi * 16 + l15;
        int n = wc * 64 + mi * 16 + l15;
        #pragma unroll
        for (int kh = 0; kh < 2; ++kh) {
            aoff[mi][kh] = m * 64 + ((quad + kh * 4) ^ (m & 7)) * 8;
            boff[mi][kh] = n * 64 + ((quad + kh * 4) ^ (n & 7)) * 8;
        }
    }

    f32x4 acc[4][4] = {};

    for (int kk = 0; kk < C; kk += 64) {
        __syncthreads();
        #pragma unroll
        for (int c2 = 0; c2 < 4; ++c2) {
            g2l16(Ah + (size_t)(i0 + mloc[c2]) * C + kk + goff[c2], As + (wave * 32 + c2 * 8) * 64);
            g2l16(Bh + (size_t)(j0 + mloc[c2]) * C + kk + goff[c2], Bs + (wave * 32 + c2 * 8) * 64);
        }
        __syncthreads();
        half8 af[2][4], bf[2][4];
        #pragma unroll
        for (int kh = 0; kh < 2; ++kh)
            #pragma unroll
            for (int mi = 0; mi < 4; ++mi) {
                af[kh][mi] = *(const half8*)(As + aoff[mi][kh]);
                bf[kh][mi] = *(const half8*)(Bs + boff[mi][kh]);
            }
        #pragma unroll
        for (int kh = 0; kh < 2; ++kh)
            #pragma unroll
            for (int mi = 0; mi < 4; ++mi)
                #pragma unroll
                for (int ni = 0; ni < 4; ++ni)
                    acc[mi][ni] = __builtin_amdgcn_mfma_f32_16x16x32_f16(af[kh][mi], bf[kh][ni], acc[mi][ni], 0, 0, 0);
    }

    #pragma unroll
    for (int mi = 0; mi < 4; ++mi) {
        int row = i0 + wr * 64 + mi * 16 + quad * 4;
        #pragma unroll
        for (int ni = 0; ni < 4; ++ni) {
            int col = j0 + wc * 64 + ni * 16 + l15;
            #pragma unroll
            for (int r = 0; r < 4; ++r)
                D0h[(size_t)(row + r) * P + col] = (_Float16)acc[mi][ni][r];
        }
    }
}

// ---------------- 9-shift score + argmax, 4 j per lane via half4 loads + lane shuffles ----------------
__global__ __launch_bounds__(256) void k_argmax(const _Float16* __restrict__ D0h,
                                                const float* __restrict__ inv_sn,
                                                int* __restrict__ idxOut) {
    const int i = blockIdx.x;
    const int ih = i >> 6, iw = i & 63;
    const int wave = threadIdx.x >> 6, l = threadIdx.x & 63, l15 = l & 15;
    int rb[9];
    #pragma unroll
    for (int t = 0; t < 9; ++t) {
        int dh = t / 3 - 1, dw = t % 3 - 1;
        rb[t] = (refl(ih + dh) * 64 + refl(iw + dw)) * P;
    }
    float best = -1e30f;
    int bidx = 0;
    #pragma unroll
    for (int s = 0; s < 4; ++s) {
        const int ws = wave * 4 + s;           // wave's j range contiguous & ascending
        const int j0 = ws * 256 + l * 4;
        const int jh = j0 >> 6;
        const int jw0 = l15 * 4;
        const int rs0 = (jh == 0) ? 1 : jh - 1;
        const int rs2 = (jh == 63) ? 62 : jh + 1;
        const int cb[3] = { rs0 * 64 + jw0, jh * 64 + jw0, rs2 * 64 + jw0 };

        float f[4] = {0.f, 0.f, 0.f, 0.f};
        #pragma unroll
        for (int dh = 0; dh < 3; ++dh) {
            const uint2 vm = *(const uint2*)(D0h + rb[dh * 3 + 0] + cb[dh]);  // dw=-1 row
            const uint2 vc = *(const uint2*)(D0h + rb[dh * 3 + 1] + cb[dh]);  // dw= 0 row
            const uint2 vp = *(const uint2*)(D0h + rb[dh * 3 + 2] + cb[dh]);  // dw=+1 row
            unsigned prev_hi = (unsigned)__shfl((int)vm.y, l - 1);
            unsigned next_lo = (unsigned)__shfl((int)vp.x, l + 1);
            unsigned left16  = ((l15 == 0) ? vm.x : prev_hi) >> 16;            // refl(jw0-1)
            unsigned right16 = ((l15 == 15) ? vp.y : next_lo) & 0xffffu;       // refl(jw0+4)
            unsigned wl0 = left16 | (vm.x << 16);
            unsigned wl1 = (vm.x >> 16) | (vm.y << 16);
            unsigned wr0 = (vp.x >> 16) | (vp.y << 16);
            unsigned wr1 = (vp.y >> 16) | (right16 << 16);
            half2v a0 = __builtin_bit_cast(half2v, wl0), a1 = __builtin_bit_cast(half2v, wl1);
            half2v b0 = __builtin_bit_cast(half2v, vc.x), b1 = __builtin_bit_cast(half2v, vc.y);
            half2v c0 = __builtin_bit_cast(half2v, wr0), c1 = __builtin_bit_cast(half2v, wr1);
            f[0] += (float)a0[0] + (float)b0[0] + (float)c0[0];
            f[1] += (float)a0[1] + (float)b0[1] + (float)c0[1];
            f[2] += (float)a1[0] + (float)b1[0] + (float)c1[0];
            f[3] += (float)a1[1] + (float)b1[1] + (float)c1[1];
        }
        const float4 is = *(const float4*)(inv_sn + j0);
        float v0 = f[0] * is.x, v1 = f[1] * is.y, v2 = f[2] * is.z, v3 = f[3] * is.w;
        if (v0 > best) { best = v0; bidx = j0; }
        if (v1 > best) { best = v1; bidx = j0 + 1; }
        if (v2 > best) { best = v2; bidx = j0 + 2; }
        if (v3 > best) { best = v3; bidx = j0 + 3; }
    }
    __shared__ float bv[256];
    __shared__ int   bi[256];
    bv[threadIdx.x] = best;
    bi[threadIdx.x] = bidx;
    __syncthreads();
    for (int t = 128; t > 0; t >>= 1) {
        if (threadIdx.x < t) {
            float ov = bv[threadIdx.x + t];
            int   oi = bi[threadIdx.x + t];
            if (ov > bv[threadIdx.x] || (ov == bv[threadIdx.x] && oi < bi[threadIdx.x])) {
                bv[threadIdx.x] = ov;
                bi[threadIdx.x] = oi;
            }
        }
        __syncthreads();
    }
    if (threadIdx.x == 0) idxOut[i] = bi[0];
}

// ---------------- build masked fp16 matrices ----------------
__global__ void k_build(const float* __restrict__ style, const float* __restrict__ input,
                        const float* __restrict__ mask, const int* __restrict__ idx,
                        _Float16* __restrict__ fc, _Float16* __restrict__ fg) {
    int t = blockIdx.x * 256 + threadIdx.x;
    int e0 = t * 8;
    int p0 = e0 & (P - 1), c = e0 >> 12;
    half8 vg, vc;
    #pragma unroll
    for (int u = 0; u < 8; ++u) {
        float m = mask[p0 + u];
        vg[u] = (_Float16)(input[e0 + u] * m);
        vc[u] = (_Float16)(style[(c << 12) + idx[p0 + u]] * m);
    }
    *(half8*)(fg + e0) = vg;
    *(half8*)(fc + e0) = vc;
}

// ---------------- gram diff partials: part[z] = (fg fg^T - fc fc^T) over K-chunk z*256 ----------------
__global__ __launch_bounds__(256) void k_gram(const _Float16* __restrict__ fg,
                                              const _Float16* __restrict__ fc,
                                              float* __restrict__ part) {
    const int z = blockIdx.z;
    const int p0 = z * 256;
    const int wave = threadIdx.x >> 6, lane = threadIdx.x & 63;
    const int wr = wave >> 1, wc = wave & 1, quad = lane >> 4, l15 = lane & 15;
    const int a0 = blockIdx.y * 128 + wr * 64, b0 = blockIdx.x * 128 + wc * 64;

    f32x4 accg[4][4] = {};
    f32x4 accc[4][4] = {};
    for (int ks = 0; ks < 256; ks += 32) {
        int kbase = p0 + ks + quad * 8;
        half8 af[4], bf[4];
        #pragma unroll
        for (int mi = 0; mi < 4; ++mi) af[mi] = *(const half8*)(fg + (size_t)(a0 + mi * 16 + l15) * P + kbase);
        #pragma unroll
        for (int ni = 0; ni < 4; ++ni) bf[ni] = *(const half8*)(fg + (size_t)(b0 + ni * 16 + l15) * P + kbase);
        #pragma unroll
        for (int mi = 0; mi < 4; ++mi)
            #pragma unroll
            for (int ni = 0; ni < 4; ++ni)
                accg[mi][ni] = __builtin_amdgcn_mfma_f32_16x16x32_f16(af[mi], bf[ni], accg[mi][ni], 0, 0, 0);
        #pragma unroll
        for (int mi = 0; mi < 4; ++mi) af[mi] = *(const half8*)(fc + (size_t)(a0 + mi * 16 + l15) * P + kbase);
        #pragma unroll
        for (int ni = 0; ni < 4; ++ni) bf[ni] = *(const half8*)(fc + (size_t)(b0 + ni * 16 + l15) * P + kbase);
        #pragma unroll
        for (int mi = 0; mi < 4; ++mi)
            #pragma unroll
            for (int ni = 0; ni < 4; ++ni)
                accc[mi][ni] = __builtin_amdgcn_mfma_f32_16x16x32_f16(af[mi], bf[ni], accc[mi][ni], 0, 0, 0);
    }
    #pragma unroll
    for (int mi = 0; mi < 4; ++mi)
        #pragma unroll
        for (int ni = 0; ni < 4; ++ni)
            #pragma unroll
            for (int r = 0; r < 4; ++r)
                part[(size_t)z * CC + (size_t)(a0 + mi * 16 + quad * 4 + r) * C + b0 + ni * 16 + l15]
                    = accg[mi][ni][r] - accc[mi][ni][r];
}

// ---------------- loss: (sum_z part)^2 reduced ----------------
__global__ void k_loss(const float* __restrict__ part, float* __restrict__ acc) {
    int e = blockIdx.x * 256 + threadIdx.x;
    float d = 0.f;
    #pragma unroll
    for (int z = 0; z < 16; ++z) d += part[(size_t)z * CC + e];
    __shared__ float red[256];
    red[threadIdx.x] = d * d;
    __syncthreads();
    for (int t = 128; t > 0; t >>= 1) {
        if (threadIdx.x < t) red[threadIdx.x] += red[threadIdx.x + t];
        __syncthreads();
    }
    if (threadIdx.x == 0) atomicAdd(acc, red[0]);
}

__global__ void k_final(const float* __restrict__ msum, const float* __restrict__ acc,
                        float* __restrict__ out) {
    float m = msum[0];
    out[0] = acc[0] * 100.0f / (m * m * 262144.0f);
}

extern "C" void kernel_launch(void* const* d_in, const int* in_sizes, int n_in,
                              void* d_out, int out_size, void* d_ws, size_t ws_size,
                              hipStream_t stream) {
    (void)in_sizes; (void)n_in; (void)out_size; (void)ws_size;
    const float* content = (const float*)d_in[0];
    const float* style   = (const float*)d_in[1];
    const float* input   = (const float*)d_in[2];
    const float* mask    = (const float*)d_in[3];

    char* ws = (char*)d_ws;
    _Float16* D0h  = (_Float16*)ws;                        // 32 MB (dead after k_argmax)
    float*    part = (float*)ws;                           // 16 MB (overlays D0h)
    _Float16* Ah   = (_Float16*)(ws + (32u << 20));        // 4 MB
    _Float16* Bh   = (_Float16*)(ws + (36u << 20));        // 4 MB
    _Float16* fg_h = (_Float16*)(ws + (40u << 20));        // 4 MB
    _Float16* fc_h = (_Float16*)(ws + (44u << 20));        // 4 MB
    float*    small = (float*)(ws + (48u << 20));
    float* sqn_s  = small;            // 4096
    float* inv_sn = small + 4096;     // 4096
    float* msum   = small + 8192;
    float* acc    = small + 8193;
    int*   idx    = (int*)(small + 8194);
    float* out = (float*)d_out;

    k_init  <<<17, 256, 0, stream>>>(small);
    k_prep  <<<512, 256, 0, stream>>>(content, style, Ah, Bh, sqn_s);
    k_pnorm <<<16, 256, 0, stream>>>(sqn_s, mask, inv_sn, msum);
    k_gemm16<<<dim3(32, 32), 256, 0, stream>>>(Ah, Bh, D0h);
    k_argmax<<<4096, 256, 0, stream>>>(D0h, inv_sn, idx);
    k_build <<<1024, 256, 0, stream>>>(style, input, mask, idx, fc_h, fg_h);
    k_gram  <<<dim3(4, 4, 16), 256, 0, stream>>>(fg_h, fc_h, part);
    k_loss  <<<1024, 256, 0, stream>>>(part, acc);
    k_final <<<1, 1, 0, stream>>>(msum, acc, out);
}